// Round 1
// baseline (1963.218 us; speedup 1.0000x reference)
//
#include <hip/hip_runtime.h>
#include <math.h>

#define HPIX 256
#define WPIX 256
#define NPIX (HPIX * WPIX)
#define DIM 96
#define QKVC 288
#define NHEAD 8
#define CPH 12
#define EPSN 1e-12f

// ---------------- K1: 1x1 conv x(96ch) -> qkv1(288ch) ----------------
// grid (NPIX/256, 288, nb), block 256
__global__ __launch_bounds__(256) void k_conv1x1_qkv(
    const float* __restrict__ x, const float* __restrict__ w,
    float* __restrict__ out, int b0) {
  int p = blockIdx.x * 256 + threadIdx.x;
  int o = blockIdx.y;
  const float* xb = x + (size_t)(b0 + blockIdx.z) * DIM * NPIX;
  const float* wo = w + o * DIM;
  float acc = 0.f;
  #pragma unroll 8
  for (int i = 0; i < DIM; ++i)
    acc = fmaf(wo[i], xb[(size_t)i * NPIX + p], acc);
  out[((size_t)blockIdx.z * QKVC + o) * NPIX + p] = acc;
}

// ---------------- K2: depthwise 3x3, zero pad 1 ----------------
// grid (NPIX/256, 288, nb), block 256
__global__ __launch_bounds__(256) void k_dw3x3(
    const float* __restrict__ in, const float* __restrict__ w,
    float* __restrict__ out) {
  int p = blockIdx.x * 256 + threadIdx.x;
  int ch = blockIdx.y;
  size_t base = ((size_t)blockIdx.z * QKVC + ch) * NPIX;
  int y = p >> 8, x = p & 255;
  const float* wc = w + ch * 9;
  float acc = 0.f;
  #pragma unroll
  for (int dy = -1; dy <= 1; ++dy) {
    int yy = y + dy;
    if (yy < 0 || yy >= HPIX) continue;
    #pragma unroll
    for (int dx = -1; dx <= 1; ++dx) {
      int xx = x + dx;
      if (xx < 0 || xx >= WPIX) continue;
      acc = fmaf(wc[(dy + 1) * 3 + (dx + 1)], in[base + (size_t)yy * WPIX + xx], acc);
    }
  }
  out[base + p] = acc;
}

// ---------------- K3: per-(b,h,c) gram + softmax chain -> attn[16][16] ----------------
// grid (96, nb), block 256. thread t -> (n = t>>4, m = t&15)
__global__ __launch_bounds__(256) void k_attn(
    const float* __restrict__ qkv2, const float* __restrict__ mask,
    const float* __restrict__ tx, const float* __restrict__ tm,
    float* __restrict__ attnbuf, int b0) {
  int g = blockIdx.x;   // h*12 + c
  int lb = blockIdx.y;  // local batch
  int h = g / CPH;
  int t = threadIdx.x;
  int n = t >> 4, m = t & 15;

  __shared__ float qT[16 * 260];
  __shared__ float kT[16 * 260];
  __shared__ float mT[16 * 260];
  __shared__ float sq[16], sk[16];

  const float* qb = qkv2 + ((size_t)lb * QKVC + g) * NPIX;
  const float* kb = qkv2 + ((size_t)lb * QKVC + DIM + g) * NPIX;
  const float* mb = mask + ((size_t)(b0 + lb) * DIM + g) * NPIX;

  float gqk = 0.f, gmm = 0.f, dq = 0.f, dk = 0.f;

  for (int chunk = 0; chunk < 16; ++chunk) {
    __syncthreads();
    int hh0 = (chunk << 2) + (t >> 6);  // hh row for this lane group
    int w0 = t & 63;
    #pragma unroll
    for (int r = 0; r < 16; ++r) {  // r = block index h1*4+w1
      size_t off = (size_t)(((r >> 2) << 6) + hh0) * WPIX + ((r & 3) << 6) + w0;
      qT[r * 260 + t] = qb[off];
      kT[r * 260 + t] = kb[off];
      mT[r * 260 + t] = mb[off];
    }
    __syncthreads();
    const float4* q4  = (const float4*)(qT + n * 260);
    const float4* k4  = (const float4*)(kT + m * 260);
    const float4* mn4 = (const float4*)(mT + n * 260);
    const float4* mm4 = (const float4*)(mT + m * 260);
    #pragma unroll 4
    for (int jq = 0; jq < 64; ++jq) {
      float4 a = q4[jq], b = k4[jq];
      gqk = fmaf(a.x, b.x, fmaf(a.y, b.y, fmaf(a.z, b.z, fmaf(a.w, b.w, gqk))));
      float4 c = mn4[jq], d = mm4[jq];
      gmm = fmaf(c.x, d.x, fmaf(c.y, d.y, fmaf(c.z, d.z, fmaf(c.w, d.w, gmm))));
    }
    // diagonal (row norms): thread t sums row n over lanes m strided 16
    const float* qr = qT + n * 260;
    const float* kr = kT + n * 260;
    #pragma unroll
    for (int jj = 0; jj < 16; ++jj) {
      float qv = qr[m + 16 * jj]; dq = fmaf(qv, qv, dq);
      float kv = kr[m + 16 * jj]; dk = fmaf(kv, kv, dk);
    }
  }

  #pragma unroll
  for (int off = 8; off; off >>= 1) {
    dq += __shfl_xor(dq, off, 16);
    dk += __shfl_xor(dk, off, 16);
  }
  if (m == 0) { sq[n] = dq; sk[n] = dk; }
  __syncthreads();

  float qn = fmaxf(sqrtf(sq[n]), EPSN);
  float km = fmaxf(sqrtf(sk[m]), EPSN);

  // attn_x = softmax_m( (q̂·k̂) * temp_x[h] )
  float ax = gqk / (qn * km) * tx[h];
  float r0 = ax;
  #pragma unroll
  for (int off = 8; off; off >>= 1) r0 = fmaxf(r0, __shfl_xor(r0, off, 16));
  float e0 = expf(ax - r0), es0 = e0;
  #pragma unroll
  for (int off = 8; off; off >>= 1) es0 += __shfl_xor(es0, off, 16);
  float attx = e0 / es0;

  // attn_m = softmax_m( l2norm_row( (qm·qm) * temp_m[h] ) )
  float am = gmm * tm[h];
  float s2 = am * am;
  #pragma unroll
  for (int off = 8; off; off >>= 1) s2 += __shfl_xor(s2, off, 16);
  am = am / fmaxf(sqrtf(s2), EPSN);
  float r1 = am;
  #pragma unroll
  for (int off = 8; off; off >>= 1) r1 = fmaxf(r1, __shfl_xor(r1, off, 16));
  float e1 = expf(am - r1), es1 = e1;
  #pragma unroll
  for (int off = 8; off; off >>= 1) es1 += __shfl_xor(es1, off, 16);
  float attm = e1 / es1;

  // attn = softmax_m(attn_x + attn_m)
  float aa = attx + attm;
  float r2 = aa;
  #pragma unroll
  for (int off = 8; off; off >>= 1) r2 = fmaxf(r2, __shfl_xor(r2, off, 16));
  float e2 = expf(aa - r2), es2 = e2;
  #pragma unroll
  for (int off = 8; off; off >>= 1) es2 += __shfl_xor(es2, off, 16);

  attnbuf[(((size_t)lb * DIM + g) << 8) + t] = e2 / es2;
}

// ---------------- K4: out_blk = attn @ v, written un-blockified ----------------
// grid (64 (hh), 96 (g), nb), block 256
__global__ __launch_bounds__(256) void k_pv(
    const float* __restrict__ qkv2, const float* __restrict__ attnbuf,
    float* __restrict__ tout) {
  int hh = blockIdx.x;
  int g = blockIdx.y;
  int lb = blockIdx.z;
  int t = threadIdx.x;
  int ww = t & 63, grp = t >> 6;

  __shared__ float vt[16][64];
  __shared__ float at[16][16];

  const float* vb = qkv2 + ((size_t)lb * QKVC + 2 * DIM + g) * NPIX;
  #pragma unroll
  for (int jj = 0; jj < 4; ++jj) {
    int mm = jj * 4 + grp;
    vt[mm][ww] = vb[(size_t)(((mm >> 2) << 6) + hh) * WPIX + ((mm & 3) << 6) + ww];
  }
  at[t >> 4][t & 15] = attnbuf[(((size_t)lb * DIM + g) << 8) + t];
  __syncthreads();

  float* ob = tout + ((size_t)lb * DIM + g) * NPIX;
  #pragma unroll
  for (int jj = 0; jj < 4; ++jj) {
    int nn = jj * 4 + grp;
    float acc = 0.f;
    #pragma unroll
    for (int mm = 0; mm < 16; ++mm)
      acc = fmaf(at[nn][mm], vt[mm][ww], acc);
    ob[(size_t)(((nn >> 2) << 6) + hh) * WPIX + ((nn & 3) << 6) + ww] = acc;
  }
}

// ---------------- K5: 1x1 proj 96 -> 96 ----------------
// grid (NPIX/256, 96, nb), block 256
__global__ __launch_bounds__(256) void k_proj(
    const float* __restrict__ tin, const float* __restrict__ w,
    float* __restrict__ out, int b0) {
  int p = blockIdx.x * 256 + threadIdx.x;
  int o = blockIdx.y;
  const float* tb = tin + (size_t)blockIdx.z * DIM * NPIX;
  const float* wo = w + o * DIM;
  float acc = 0.f;
  #pragma unroll 8
  for (int i = 0; i < DIM; ++i)
    acc = fmaf(wo[i], tb[(size_t)i * NPIX + p], acc);
  out[((size_t)(b0 + blockIdx.z) * DIM + o) * NPIX + p] = acc;
}

extern "C" void kernel_launch(void* const* d_in, const int* in_sizes, int n_in,
                              void* d_out, int out_size, void* d_ws, size_t ws_size,
                              hipStream_t stream) {
  const float* x      = (const float*)d_in[0];
  const float* mask   = (const float*)d_in[1];
  const float* w_qkv  = (const float*)d_in[2];
  const float* w_dw   = (const float*)d_in[3];
  const float* w_proj = (const float*)d_in[4];
  const float* tx     = (const float*)d_in[5];
  const float* tm     = (const float*)d_in[6];
  float* out = (float*)d_out;

  const size_t qkvBytes = (size_t)QKVC * NPIX * sizeof(float);  // 75.5 MB per batch
  const size_t attnBytesPerB = (size_t)DIM * 256 * sizeof(float);

  // full-batch path needs 2*4*qkvBytes + attn; per-batch path needs 2*qkvBytes + attn
  int nb, npass;
  if (ws_size >= 8 * qkvBytes + 4 * attnBytesPerB) { nb = 4; npass = 1; }
  else                                             { nb = 1; npass = 4; }

  char* base = (char*)d_ws;
  float* qkv1 = (float*)base;                                   // nb * qkvBytes (later reused as t)
  float* qkv2 = (float*)(base + (size_t)nb * qkvBytes);         // nb * qkvBytes
  float* attn = (float*)(base + 2 * (size_t)nb * qkvBytes);     // nb * attnBytesPerB
  float* tbuf = qkv1;  // alias: qkv1 dead after k_dw3x3

  dim3 blk(256);
  for (int pass = 0; pass < npass; ++pass) {
    int b0 = pass * nb;
    k_conv1x1_qkv<<<dim3(NPIX / 256, QKVC, nb), blk, 0, stream>>>(x, w_qkv, qkv1, b0);
    k_dw3x3<<<dim3(NPIX / 256, QKVC, nb), blk, 0, stream>>>(qkv1, w_dw, qkv2);
    k_attn<<<dim3(DIM, nb), blk, 0, stream>>>(qkv2, mask, tx, tm, attn, b0);
    k_pv<<<dim3(64, DIM, nb), blk, 0, stream>>>(qkv2, attn, tbuf);
    k_proj<<<dim3(NPIX / 256, DIM, nb), blk, 0, stream>>>(tbuf, w_proj, out, b0);
  }
}

// Round 2
// 796.178 us; speedup vs baseline: 2.4658x; 2.4658x over previous
//
#include <hip/hip_runtime.h>
#include <math.h>

#define HPIX 256
#define WPIX 256
#define NPIX (HPIX * WPIX)
#define DIM 96
#define QKVC 288
#define NHEAD 8
#define CPH 12
#define EPSN 1e-12f

// ---------------- K1/K5: 1x1 conv as skinny GEMM, 16 och x 2 px per thread ----
// grid (NPIX/512, OC/16, nb), block 256
template<int OC>
__global__ __launch_bounds__(256) void k_conv1x1_t(
    const float* __restrict__ xin, const float* __restrict__ w,
    float* __restrict__ out) {
  int t = threadIdx.x;
  int p0 = blockIdx.x * 512 + t * 2;
  int ob = blockIdx.y * 16;
  const float* xb = xin + (size_t)blockIdx.z * DIM * NPIX + p0;
  float2 acc[16];
  #pragma unroll
  for (int o = 0; o < 16; ++o) acc[o] = make_float2(0.f, 0.f);
  for (int i = 0; i < DIM; i += 4) {
    float2 xv[4];
    #pragma unroll
    for (int ii = 0; ii < 4; ++ii)
      xv[ii] = *(const float2*)(xb + (size_t)(i + ii) * NPIX);
    #pragma unroll
    for (int o = 0; o < 16; ++o) {
      #pragma unroll
      for (int ii = 0; ii < 4; ++ii) {
        float wv = w[(size_t)(ob + o) * DIM + i + ii];  // block-uniform -> s_load
        acc[o].x = fmaf(wv, xv[ii].x, acc[o].x);
        acc[o].y = fmaf(wv, xv[ii].y, acc[o].y);
      }
    }
  }
  float* op = out + (size_t)blockIdx.z * OC * NPIX + p0;
  #pragma unroll
  for (int o = 0; o < 16; ++o)
    *(float2*)(op + (size_t)(ob + o) * NPIX) = acc[o];
}

// ---------------- K2: depthwise 3x3, zero pad 1, 4 px per thread ----------------
// grid (NPIX/1024, 288, nb), block 256
__global__ __launch_bounds__(256) void k_dw3x3(
    const float* __restrict__ in, const float* __restrict__ w,
    float* __restrict__ out) {
  int t = threadIdx.x;
  int p0 = (blockIdx.x * 256 + t) * 4;
  int ch = blockIdx.y;
  size_t base = ((size_t)blockIdx.z * QKVC + ch) * NPIX;
  int y = p0 >> 8, x0 = p0 & 255;
  const float* wc = w + ch * 9;
  float a0 = 0.f, a1 = 0.f, a2 = 0.f, a3 = 0.f;
  #pragma unroll
  for (int dy = -1; dy <= 1; ++dy) {
    int yy = y + dy;
    if (yy < 0 || yy >= HPIX) continue;
    const float* row = in + base + (size_t)yy * WPIX + x0;
    float4 c = *(const float4*)row;
    float l = (x0 > 0) ? row[-1] : 0.f;
    float r = (x0 < 252) ? row[4] : 0.f;
    float w0 = wc[(dy + 1) * 3], w1 = wc[(dy + 1) * 3 + 1], w2 = wc[(dy + 1) * 3 + 2];
    a0 = fmaf(w0, l,   fmaf(w1, c.x, fmaf(w2, c.y, a0)));
    a1 = fmaf(w0, c.x, fmaf(w1, c.y, fmaf(w2, c.z, a1)));
    a2 = fmaf(w0, c.y, fmaf(w1, c.z, fmaf(w2, c.w, a2)));
    a3 = fmaf(w0, c.z, fmaf(w1, c.w, fmaf(w2, r,   a3)));
  }
  *(float4*)(out + base + p0) = make_float4(a0, a1, a2, a3);
}

// ---------------- K3: per-(b,h,c) gram + softmax chain -> attn[16][16] ----------------
// grid (96, nb), block 256. thread t -> (n = t>>4, m = t&15)
__global__ __launch_bounds__(256) void k_attn(
    const float* __restrict__ qkv2, const float* __restrict__ mask,
    const float* __restrict__ tx, const float* __restrict__ tm,
    float* __restrict__ attnbuf, int b0) {
  int g = blockIdx.x;   // h*12 + c
  int lb = blockIdx.y;  // local batch
  int h = g / CPH;
  int t = threadIdx.x;
  int n = t >> 4, m = t & 15;

  __shared__ float qT[16 * 260];
  __shared__ float kT[16 * 260];
  __shared__ float mT[16 * 260];
  __shared__ float sq[16], sk[16];

  const float* qb = qkv2 + ((size_t)lb * QKVC + g) * NPIX;
  const float* kb = qkv2 + ((size_t)lb * QKVC + DIM + g) * NPIX;
  const float* mb = mask + ((size_t)(b0 + lb) * DIM + g) * NPIX;

  float gqk = 0.f, gmm = 0.f, dq = 0.f, dk = 0.f;

  for (int chunk = 0; chunk < 16; ++chunk) {
    __syncthreads();
    int hh0 = (chunk << 2) + (t >> 6);  // hh row for this lane group
    int w0 = t & 63;
    #pragma unroll
    for (int r = 0; r < 16; ++r) {  // r = block index h1*4+w1
      size_t off = (size_t)(((r >> 2) << 6) + hh0) * WPIX + ((r & 3) << 6) + w0;
      qT[r * 260 + t] = qb[off];
      kT[r * 260 + t] = kb[off];
      mT[r * 260 + t] = mb[off];
    }
    __syncthreads();
    const float4* q4  = (const float4*)(qT + n * 260);
    const float4* k4  = (const float4*)(kT + m * 260);
    const float4* mn4 = (const float4*)(mT + n * 260);
    const float4* mm4 = (const float4*)(mT + m * 260);
    #pragma unroll 4
    for (int jq = 0; jq < 64; ++jq) {
      float4 a = q4[jq], b = k4[jq];
      gqk = fmaf(a.x, b.x, fmaf(a.y, b.y, fmaf(a.z, b.z, fmaf(a.w, b.w, gqk))));
      float4 c = mn4[jq], d = mm4[jq];
      gmm = fmaf(c.x, d.x, fmaf(c.y, d.y, fmaf(c.z, d.z, fmaf(c.w, d.w, gmm))));
    }
    // diagonal (row norms): thread t sums row n over lanes m strided 16
    const float* qr = qT + n * 260;
    const float* kr = kT + n * 260;
    #pragma unroll
    for (int jj = 0; jj < 16; ++jj) {
      float qv = qr[m + 16 * jj]; dq = fmaf(qv, qv, dq);
      float kv = kr[m + 16 * jj]; dk = fmaf(kv, kv, dk);
    }
  }

  #pragma unroll
  for (int off = 8; off; off >>= 1) {
    dq += __shfl_xor(dq, off, 16);
    dk += __shfl_xor(dk, off, 16);
  }
  if (m == 0) { sq[n] = dq; sk[n] = dk; }
  __syncthreads();

  float qn = fmaxf(sqrtf(sq[n]), EPSN);
  float km = fmaxf(sqrtf(sk[m]), EPSN);

  float ax = gqk / (qn * km) * tx[h];
  float r0 = ax;
  #pragma unroll
  for (int off = 8; off; off >>= 1) r0 = fmaxf(r0, __shfl_xor(r0, off, 16));
  float e0 = expf(ax - r0), es0 = e0;
  #pragma unroll
  for (int off = 8; off; off >>= 1) es0 += __shfl_xor(es0, off, 16);
  float attx = e0 / es0;

  float am = gmm * tm[h];
  float s2 = am * am;
  #pragma unroll
  for (int off = 8; off; off >>= 1) s2 += __shfl_xor(s2, off, 16);
  am = am / fmaxf(sqrtf(s2), EPSN);
  float r1 = am;
  #pragma unroll
  for (int off = 8; off; off >>= 1) r1 = fmaxf(r1, __shfl_xor(r1, off, 16));
  float e1 = expf(am - r1), es1 = e1;
  #pragma unroll
  for (int off = 8; off; off >>= 1) es1 += __shfl_xor(es1, off, 16);
  float attm = e1 / es1;

  float aa = attx + attm;
  float r2 = aa;
  #pragma unroll
  for (int off = 8; off; off >>= 1) r2 = fmaxf(r2, __shfl_xor(r2, off, 16));
  float e2 = expf(aa - r2), es2 = e2;
  #pragma unroll
  for (int off = 8; off; off >>= 1) es2 += __shfl_xor(es2, off, 16);

  attnbuf[(((size_t)lb * DIM + g) << 8) + t] = e2 / es2;
}

// ---------------- K4: out_blk = attn @ v, written un-blockified ----------------
// grid (64 (hh), 96 (g), nb), block 256
__global__ __launch_bounds__(256) void k_pv(
    const float* __restrict__ qkv2, const float* __restrict__ attnbuf,
    float* __restrict__ tout) {
  int hh = blockIdx.x;
  int g = blockIdx.y;
  int lb = blockIdx.z;
  int t = threadIdx.x;
  int ww = t & 63, grp = t >> 6;

  __shared__ float vt[16][64];
  __shared__ float at[16][16];

  const float* vb = qkv2 + ((size_t)lb * QKVC + 2 * DIM + g) * NPIX;
  #pragma unroll
  for (int jj = 0; jj < 4; ++jj) {
    int mm = jj * 4 + grp;
    vt[mm][ww] = vb[(size_t)(((mm >> 2) << 6) + hh) * WPIX + ((mm & 3) << 6) + ww];
  }
  at[t >> 4][t & 15] = attnbuf[(((size_t)lb * DIM + g) << 8) + t];
  __syncthreads();

  float* ob = tout + ((size_t)lb * DIM + g) * NPIX;
  #pragma unroll
  for (int jj = 0; jj < 4; ++jj) {
    int nn = jj * 4 + grp;
    float acc = 0.f;
    #pragma unroll
    for (int mm = 0; mm < 16; ++mm)
      acc = fmaf(at[nn][mm], vt[mm][ww], acc);
    ob[(size_t)(((nn >> 2) << 6) + hh) * WPIX + ((nn & 3) << 6) + ww] = acc;
  }
}

extern "C" void kernel_launch(void* const* d_in, const int* in_sizes, int n_in,
                              void* d_out, int out_size, void* d_ws, size_t ws_size,
                              hipStream_t stream) {
  const float* x      = (const float*)d_in[0];
  const float* mask   = (const float*)d_in[1];
  const float* w_qkv  = (const float*)d_in[2];
  const float* w_dw   = (const float*)d_in[3];
  const float* w_proj = (const float*)d_in[4];
  const float* tx     = (const float*)d_in[5];
  const float* tm     = (const float*)d_in[6];
  float* out = (float*)d_out;

  const size_t qkvBytes = (size_t)QKVC * NPIX * sizeof(float);  // 75.5 MB per batch
  const size_t attnBytesPerB = (size_t)DIM * 256 * sizeof(float);

  int nb, npass;
  if (ws_size >= 8 * qkvBytes + 4 * attnBytesPerB) { nb = 4; npass = 1; }
  else                                             { nb = 1; npass = 4; }

  char* base = (char*)d_ws;
  float* qkv1 = (float*)base;                                   // nb * qkvBytes (later reused as t)
  float* qkv2 = (float*)(base + (size_t)nb * qkvBytes);         // nb * qkvBytes
  float* attn = (float*)(base + 2 * (size_t)nb * qkvBytes);     // nb * attnBytesPerB
  float* tbuf = qkv1;  // alias: qkv1 dead after k_dw3x3

  dim3 blk(256);
  for (int pass = 0; pass < npass; ++pass) {
    int b0 = pass * nb;
    const float* xb = x + (size_t)b0 * DIM * NPIX;
    k_conv1x1_t<QKVC><<<dim3(NPIX / 512, QKVC / 16, nb), blk, 0, stream>>>(xb, w_qkv, qkv1);
    k_dw3x3<<<dim3(NPIX / 1024, QKVC, nb), blk, 0, stream>>>(qkv1, w_dw, qkv2);
    k_attn<<<dim3(DIM, nb), blk, 0, stream>>>(qkv2, mask, tx, tm, attn, b0);
    k_pv<<<dim3(64, DIM, nb), blk, 0, stream>>>(qkv2, attn, tbuf);
    k_conv1x1_t<DIM><<<dim3(NPIX / 512, DIM / 16, nb), blk, 0, stream>>>(
        tbuf, w_proj, out + (size_t)b0 * DIM * NPIX);
  }
}

// Round 3
// 597.399 us; speedup vs baseline: 3.2863x; 1.3327x over previous
//
#include <hip/hip_runtime.h>
#include <math.h>

#define HPIX 256
#define WPIX 256
#define NPIX (HPIX * WPIX)
#define DIM 96
#define QKVC 288
#define NHEAD 8
#define CPH 12
#define EPSN 1e-12f
#define PSTRIDE 544  // per (b,g,chunk) partial record: 256 gqk + 256 gmm + 16 dq + 16 dk

// ---------------- K1/K5: 1x1 conv as skinny GEMM, 16 och x 2 px per thread ----
// grid (NPIX/512, OC/16, nb), block 256
template<int OC>
__global__ __launch_bounds__(256) void k_conv1x1_t(
    const float* __restrict__ xin, const float* __restrict__ w,
    float* __restrict__ out) {
  int t = threadIdx.x;
  int p0 = blockIdx.x * 512 + t * 2;
  int ob = blockIdx.y * 16;
  const float* xb = xin + (size_t)blockIdx.z * DIM * NPIX + p0;
  float2 acc[16];
  #pragma unroll
  for (int o = 0; o < 16; ++o) acc[o] = make_float2(0.f, 0.f);
  for (int i = 0; i < DIM; i += 4) {
    float2 xv[4];
    #pragma unroll
    for (int ii = 0; ii < 4; ++ii)
      xv[ii] = *(const float2*)(xb + (size_t)(i + ii) * NPIX);
    #pragma unroll
    for (int o = 0; o < 16; ++o) {
      #pragma unroll
      for (int ii = 0; ii < 4; ++ii) {
        float wv = w[(size_t)(ob + o) * DIM + i + ii];  // block-uniform -> s_load
        acc[o].x = fmaf(wv, xv[ii].x, acc[o].x);
        acc[o].y = fmaf(wv, xv[ii].y, acc[o].y);
      }
    }
  }
  float* op = out + (size_t)blockIdx.z * OC * NPIX + p0;
  #pragma unroll
  for (int o = 0; o < 16; ++o)
    *(float2*)(op + (size_t)(ob + o) * NPIX) = acc[o];
}

// ---------------- K2: depthwise 3x3, zero pad 1, 4 px per thread ----------------
// grid (NPIX/1024, 288, nb), block 256
__global__ __launch_bounds__(256) void k_dw3x3(
    const float* __restrict__ in, const float* __restrict__ w,
    float* __restrict__ out) {
  int t = threadIdx.x;
  int p0 = (blockIdx.x * 256 + t) * 4;
  int ch = blockIdx.y;
  size_t base = ((size_t)blockIdx.z * QKVC + ch) * NPIX;
  int y = p0 >> 8, x0 = p0 & 255;
  const float* wc = w + ch * 9;
  float a0 = 0.f, a1 = 0.f, a2 = 0.f, a3 = 0.f;
  #pragma unroll
  for (int dy = -1; dy <= 1; ++dy) {
    int yy = y + dy;
    if (yy < 0 || yy >= HPIX) continue;
    const float* row = in + base + (size_t)yy * WPIX + x0;
    float4 c = *(const float4*)row;
    float l = (x0 > 0) ? row[-1] : 0.f;
    float r = (x0 < 252) ? row[4] : 0.f;
    float w0 = wc[(dy + 1) * 3], w1 = wc[(dy + 1) * 3 + 1], w2 = wc[(dy + 1) * 3 + 2];
    a0 = fmaf(w0, l,   fmaf(w1, c.x, fmaf(w2, c.y, a0)));
    a1 = fmaf(w0, c.x, fmaf(w1, c.y, fmaf(w2, c.z, a1)));
    a2 = fmaf(w0, c.y, fmaf(w1, c.z, fmaf(w2, c.w, a2)));
    a3 = fmaf(w0, c.z, fmaf(w1, c.w, fmaf(w2, r,   a3)));
  }
  *(float4*)(out + base + p0) = make_float4(a0, a1, a2, a3);
}

// ---------------- K3a: per-(b,g,chunk) partial grams + row norms ----------------
// grid (96, 16, nb), block 256. thread t -> (n = t>>4, m = t&15)
__global__ __launch_bounds__(256) void k_attn_part(
    const float* __restrict__ qkv2, const float* __restrict__ mask,
    float* __restrict__ pbuf, int b0) {
  int g = blockIdx.x;
  int c = blockIdx.y;
  int lb = blockIdx.z;
  int t = threadIdx.x;
  int n = t >> 4, m = t & 15;

  __shared__ float qT[16 * 260];
  __shared__ float kT[16 * 260];
  __shared__ float mT[16 * 260];

  const float* qb = qkv2 + ((size_t)lb * QKVC + g) * NPIX;
  const float* kb = qkv2 + ((size_t)lb * QKVC + DIM + g) * NPIX;
  const float* mb = mask + ((size_t)(b0 + lb) * DIM + g) * NPIX;

  int hh0 = (c << 2) + (t >> 6);
  int w0 = t & 63;
  #pragma unroll
  for (int r = 0; r < 16; ++r) {  // r = spatial block h1*4+w1
    size_t off = (size_t)(((r >> 2) << 6) + hh0) * WPIX + ((r & 3) << 6) + w0;
    qT[r * 260 + t] = qb[off];
    kT[r * 260 + t] = kb[off];
    mT[r * 260 + t] = mb[off];
  }
  __syncthreads();

  float gqk = 0.f, gmm = 0.f, dq = 0.f, dk = 0.f;
  const float4* q4  = (const float4*)(qT + n * 260);
  const float4* k4  = (const float4*)(kT + m * 260);
  const float4* mn4 = (const float4*)(mT + n * 260);
  const float4* mm4 = (const float4*)(mT + m * 260);
  #pragma unroll 4
  for (int jq = 0; jq < 64; ++jq) {
    float4 a = q4[jq], b = k4[jq];
    gqk = fmaf(a.x, b.x, fmaf(a.y, b.y, fmaf(a.z, b.z, fmaf(a.w, b.w, gqk))));
    float4 cc = mn4[jq], d = mm4[jq];
    gmm = fmaf(cc.x, d.x, fmaf(cc.y, d.y, fmaf(cc.z, d.z, fmaf(cc.w, d.w, gmm))));
  }
  const float* qr = qT + n * 260;
  const float* kr = kT + n * 260;
  #pragma unroll
  for (int jj = 0; jj < 16; ++jj) {
    float qv = qr[m + 16 * jj]; dq = fmaf(qv, qv, dq);
    float kv = kr[m + 16 * jj]; dk = fmaf(kv, kv, dk);
  }
  #pragma unroll
  for (int off = 8; off; off >>= 1) {
    dq += __shfl_xor(dq, off, 16);
    dk += __shfl_xor(dk, off, 16);
  }

  float* pb = pbuf + (((size_t)lb * DIM + g) * 16 + c) * PSTRIDE;
  pb[t] = gqk;
  pb[256 + t] = gmm;
  if (m == 0) { pb[512 + n] = dq; pb[528 + n] = dk; }
}

// ---------------- K3b: reduce partials + softmax chain -> attn[16][16] ---------
// grid (96, nb), block 256
__global__ __launch_bounds__(256) void k_attn_fin(
    const float* __restrict__ pbuf, const float* __restrict__ tx,
    const float* __restrict__ tm, float* __restrict__ attnbuf) {
  int g = blockIdx.x;
  int lb = blockIdx.y;
  int h = g / CPH;
  int t = threadIdx.x;
  int n = t >> 4, m = t & 15;

  const float* pb = pbuf + ((size_t)lb * DIM + g) * 16 * PSTRIDE;
  float gqk = 0.f, gmm = 0.f, dq = 0.f, dk = 0.f;
  #pragma unroll
  for (int c = 0; c < 16; ++c) {
    const float* p = pb + c * PSTRIDE;
    gqk += p[t];
    gmm += p[256 + t];
    dq  += p[512 + n];   // row-n q norm^2 partial
    dk  += p[528 + m];   // row-m k norm^2 partial
  }

  float qn = fmaxf(sqrtf(dq), EPSN);
  float km = fmaxf(sqrtf(dk), EPSN);

  float ax = gqk / (qn * km) * tx[h];
  float r0 = ax;
  #pragma unroll
  for (int off = 8; off; off >>= 1) r0 = fmaxf(r0, __shfl_xor(r0, off, 16));
  float e0 = expf(ax - r0), es0 = e0;
  #pragma unroll
  for (int off = 8; off; off >>= 1) es0 += __shfl_xor(es0, off, 16);
  float attx = e0 / es0;

  float am = gmm * tm[h];
  float s2 = am * am;
  #pragma unroll
  for (int off = 8; off; off >>= 1) s2 += __shfl_xor(s2, off, 16);
  am = am / fmaxf(sqrtf(s2), EPSN);
  float r1 = am;
  #pragma unroll
  for (int off = 8; off; off >>= 1) r1 = fmaxf(r1, __shfl_xor(r1, off, 16));
  float e1 = expf(am - r1), es1 = e1;
  #pragma unroll
  for (int off = 8; off; off >>= 1) es1 += __shfl_xor(es1, off, 16);
  float attm = e1 / es1;

  float aa = attx + attm;
  float r2 = aa;
  #pragma unroll
  for (int off = 8; off; off >>= 1) r2 = fmaxf(r2, __shfl_xor(r2, off, 16));
  float e2 = expf(aa - r2), es2 = e2;
  #pragma unroll
  for (int off = 8; off; off >>= 1) es2 += __shfl_xor(es2, off, 16);

  attnbuf[(((size_t)lb * DIM + g) << 8) + t] = e2 / es2;
}

// ---------------- K4: out_blk = attn @ v, written un-blockified ----------------
// grid (64 (hh), 96 (g), nb), block 256
__global__ __launch_bounds__(256) void k_pv(
    const float* __restrict__ qkv2, const float* __restrict__ attnbuf,
    float* __restrict__ tout) {
  int hh = blockIdx.x;
  int g = blockIdx.y;
  int lb = blockIdx.z;
  int t = threadIdx.x;
  int ww = t & 63, grp = t >> 6;

  __shared__ float vt[16][64];
  __shared__ float at[16][16];

  const float* vb = qkv2 + ((size_t)lb * QKVC + 2 * DIM + g) * NPIX;
  #pragma unroll
  for (int jj = 0; jj < 4; ++jj) {
    int mm = jj * 4 + grp;
    vt[mm][ww] = vb[(size_t)(((mm >> 2) << 6) + hh) * WPIX + ((mm & 3) << 6) + ww];
  }
  at[t >> 4][t & 15] = attnbuf[(((size_t)lb * DIM + g) << 8) + t];
  __syncthreads();

  float* ob = tout + ((size_t)lb * DIM + g) * NPIX;
  #pragma unroll
  for (int jj = 0; jj < 4; ++jj) {
    int nn = jj * 4 + grp;
    float acc = 0.f;
    #pragma unroll
    for (int mm = 0; mm < 16; ++mm)
      acc = fmaf(at[nn][mm], vt[mm][ww], acc);
    ob[(size_t)(((nn >> 2) << 6) + hh) * WPIX + ((nn & 3) << 6) + ww] = acc;
  }
}

extern "C" void kernel_launch(void* const* d_in, const int* in_sizes, int n_in,
                              void* d_out, int out_size, void* d_ws, size_t ws_size,
                              hipStream_t stream) {
  const float* x      = (const float*)d_in[0];
  const float* mask   = (const float*)d_in[1];
  const float* w_qkv  = (const float*)d_in[2];
  const float* w_dw   = (const float*)d_in[3];
  const float* w_proj = (const float*)d_in[4];
  const float* tx     = (const float*)d_in[5];
  const float* tm     = (const float*)d_in[6];
  float* out = (float*)d_out;

  const size_t qkvBytes = (size_t)QKVC * NPIX * sizeof(float);  // 75.5 MB per batch
  const size_t attnBytesPerB = (size_t)DIM * 256 * sizeof(float);

  int nb, npass;
  if (ws_size >= 8 * qkvBytes + 4 * attnBytesPerB) { nb = 4; npass = 1; }
  else                                             { nb = 1; npass = 4; }

  char* base = (char*)d_ws;
  float* qkv1 = (float*)base;                                   // nb * qkvBytes (later reused as t)
  float* qkv2 = (float*)(base + (size_t)nb * qkvBytes);         // nb * qkvBytes
  float* attn = (float*)(base + 2 * (size_t)nb * qkvBytes);     // nb * attnBytesPerB
  float* tbuf = qkv1;  // alias: qkv1 dead after k_dw3x3
  // partials: alias into qkv1 region PAST the area k_pv/tbuf writes
  // (tbuf uses nb*DIM*NPIX floats = nb*25.2MB; qkv1 region is nb*75.5MB)
  float* pbuf = qkv1 + (size_t)nb * DIM * NPIX;

  dim3 blk(256);
  for (int pass = 0; pass < npass; ++pass) {
    int b0 = pass * nb;
    const float* xb = x + (size_t)b0 * DIM * NPIX;
    k_conv1x1_t<QKVC><<<dim3(NPIX / 512, QKVC / 16, nb), blk, 0, stream>>>(xb, w_qkv, qkv1);
    k_dw3x3<<<dim3(NPIX / 1024, QKVC, nb), blk, 0, stream>>>(qkv1, w_dw, qkv2);
    k_attn_part<<<dim3(DIM, 16, nb), blk, 0, stream>>>(qkv2, mask, pbuf, b0);
    k_attn_fin<<<dim3(DIM, nb), blk, 0, stream>>>(pbuf, tx, tm, attn);
    k_pv<<<dim3(64, DIM, nb), blk, 0, stream>>>(qkv2, attn, tbuf);
    k_conv1x1_t<DIM><<<dim3(NPIX / 512, DIM / 16, nb), blk, 0, stream>>>(
        tbuf, w_proj, out + (size_t)b0 * DIM * NPIX);
  }
}